// Round 2
// baseline (254.223 us; speedup 1.0000x reference)
//
#include <hip/hip_runtime.h>

// SMap3x3 — R5: two-phase restructure.
//
// Evidence: poison fill (1 contiguous stream, plain stores) hits 6.36 TB/s;
// our fused kernel (~49 interleaved 4KiB-granule streams per block, ~59k
// device-wide) runs at ~2.1 TB/s effective and is insensitive to NT-vs-plain
// store flavor (R4: +1.5us noise). Theory: DRAM/L2 stream-concurrency, not
// instruction selection. Fix: phase 1 computes per-pixel packed selectors
// (1 B/pixel) into d_ws; phase 2 gives each block ONE contiguous 123 KB
// write run of ONE output plane (fill-shaped write side), with selector
// (1.23 MB, L2-resident) + value planes (19.7 MB, L3-resident) as reads.
//
// Selector packing per pixel: low nibble sel_w (0..8, 15=none) for x/y/z
// planes, high nibble sel_w2 (0..8) for the r plane.
//   r<=0.5          : sel_w=15, sel_w2=4
//   r>0.5 && z>0    : sel_w=argmin, sel_w2=argmin
//   r>0.5 && z<=0   : sel_w=4,  sel_w2=4
//
// Fallback: if ws_size < 1.23 MB, launch the previous (verified) fused kernel.

constexpr int H = 480;
constexpr int W = 640;
constexpr int HW = H * W;          // 307200
constexpr int HW4 = HW / 4;        // 76800 float4 per plane
constexpr int NB = 4;              // batch
constexpr int BLK = 256;
constexpr int GRIDX = HW4 / BLK;   // 300 (exact)

constexpr int CHUNKS = 10;
constexpr int CHUNK_F4 = HW4 / CHUNKS;   // 7680 float4 per chunk
constexpr int ITERS = CHUNK_F4 / BLK;    // 30 (exact)

typedef __attribute__((ext_vector_type(4))) float fvec4;

__device__ __forceinline__ fvec4 nt_load4(const fvec4* p) {
    return __builtin_nontemporal_load(p);
}
__device__ __forceinline__ void nt_store4(fvec4* p, fvec4 v) {
    __builtin_nontemporal_store(v, p);
}

__device__ __forceinline__ unsigned char pack_sel(float rr, float zz, int i) {
    const bool ron = rr > 0.5f, zon = zz > 0.0f;
    const int sw = ron ? (zon ? i : 4) : 15;
    const int s2 = (ron && zon) ? i : 4;
    return (unsigned char)(sw | (s2 << 4));
}

// ---------------- Phase 1: per-pixel selector ----------------
__global__ __launch_bounds__(256) void smap_sel_kernel(
    const fvec4* __restrict__ z,
    const fvec4* __restrict__ r,
    const fvec4* __restrict__ kq,
    uchar4* __restrict__ sel)          // NB*HW4 uchar4 (1 B per pixel)
{
    const int hw4 = blockIdx.x * BLK + threadIdx.x;  // [0, HW4)
    const int b   = blockIdx.y;                      // [0, NB)
    const size_t pix = (size_t)b * HW4 + hw4;

    // argmin over 9 planes, per component (first-occurrence tie-break)
    const fvec4* kqb = kq + (size_t)b * 9 * HW4 + hw4;
    fvec4 best = nt_load4(kqb);
    int i0 = 0, i1 = 0, i2 = 0, i3 = 0;
#pragma unroll
    for (int k = 1; k < 9; ++k) {
        const fvec4 kk = nt_load4(kqb + (size_t)k * HW4);
        if (kk.x < best.x) { best.x = kk.x; i0 = k; }
        if (kk.y < best.y) { best.y = kk.y; i1 = k; }
        if (kk.z < best.z) { best.z = kk.z; i2 = k; }
        if (kk.w < best.w) { best.w = kk.w; i3 = k; }
    }

    const fvec4 zv = z[pix];
    const fvec4 rv = r[pix];

    uchar4 s;
    s.x = pack_sel(rv.x, zv.x, i0);
    s.y = pack_sel(rv.y, zv.y, i1);
    s.z = pack_sel(rv.z, zv.z, i2);
    s.w = pack_sel(rv.w, zv.w, i3);
    sel[pix] = s;
}

// ---------------- Phase 2: plane-specialized scatter ----------------
// grid = (36 planes, CHUNKS, NB); each block writes one contiguous
// CHUNK_F4*16 = 123 KB run of one output plane.
__global__ __launch_bounds__(256) void smap_scatter_kernel(
    const fvec4* __restrict__ x,
    const fvec4* __restrict__ y,
    const fvec4* __restrict__ z,
    const fvec4* __restrict__ r,
    const uchar4* __restrict__ sel,
    fvec4* __restrict__ out)
{
    const int p     = blockIdx.x;     // 0..35 : output plane within batch
    const int chunk = blockIdx.y;     // 0..CHUNKS-1
    const int b     = blockIdx.z;     // 0..NB-1
    const int k = p >> 2;             // window index 0..8
    const int c = p & 3;              // component: 0=x 1=y 2=z 3=r

    const fvec4* val = (c == 0) ? x : (c == 1) ? y : (c == 2) ? z : r;
    const int shift = (c < 3) ? 0 : 4;

    const size_t base = (size_t)b * HW4 + (size_t)chunk * CHUNK_F4;
    const uchar4* sb = sel + base;
    const fvec4*  vb = val + base;
    fvec4* ob = out + ((size_t)b * 36 + p) * HW4 + (size_t)chunk * CHUNK_F4;

#pragma unroll 6
    for (int it = 0; it < ITERS; ++it) {
        const int idx = it * BLK + threadIdx.x;
        const uchar4 s = sb[idx];
        const fvec4  v = vb[idx];
        fvec4 o;
        o.x = (((s.x >> shift) & 15) == k) ? v.x : 0.0f;
        o.y = (((s.y >> shift) & 15) == k) ? v.y : 0.0f;
        o.z = (((s.z >> shift) & 15) == k) ? v.z : 0.0f;
        o.w = (((s.w >> shift) & 15) == k) ? v.w : 0.0f;
        nt_store4(ob + idx, o);   // keep the 177 MB stream out of L2
    }
}

// ---------------- Fallback: previous verified fused kernel ----------------
__global__ __launch_bounds__(256) void smap3x3_fused_kernel(
    const fvec4* __restrict__ x,
    const fvec4* __restrict__ y,
    const fvec4* __restrict__ z,
    const fvec4* __restrict__ r,
    const fvec4* __restrict__ kq,
    fvec4* __restrict__ out)
{
    const int hw4 = blockIdx.x * BLK + threadIdx.x;
    const int b   = blockIdx.y;
    const size_t pix = (size_t)b * HW4 + hw4;

    const fvec4* kqb = kq + (size_t)b * 9 * HW4 + hw4;
    fvec4 best = nt_load4(kqb);
    int i0 = 0, i1 = 0, i2 = 0, i3 = 0;
#pragma unroll
    for (int k = 1; k < 9; ++k) {
        const fvec4 kk = nt_load4(kqb + (size_t)k * HW4);
        if (kk.x < best.x) { best.x = kk.x; i0 = k; }
        if (kk.y < best.y) { best.y = kk.y; i1 = k; }
        if (kk.z < best.z) { best.z = kk.z; i2 = k; }
        if (kk.w < best.w) { best.w = kk.w; i3 = k; }
    }

    const fvec4 xv = nt_load4(x + pix);
    const fvec4 yv = nt_load4(y + pix);
    const fvec4 zv = nt_load4(z + pix);
    const fvec4 rv = nt_load4(r + pix);

    int sw0, sw1, sw2, sw3, s20, s21, s22, s23;
    { const bool ron = rv.x > 0.5f, zon = zv.x > 0.0f;
      sw0 = ron ? (zon ? i0 : 4) : -1;  s20 = (ron && zon) ? i0 : 4; }
    { const bool ron = rv.y > 0.5f, zon = zv.y > 0.0f;
      sw1 = ron ? (zon ? i1 : 4) : -1;  s21 = (ron && zon) ? i1 : 4; }
    { const bool ron = rv.z > 0.5f, zon = zv.z > 0.0f;
      sw2 = ron ? (zon ? i2 : 4) : -1;  s22 = (ron && zon) ? i2 : 4; }
    { const bool ron = rv.w > 0.5f, zon = zv.w > 0.0f;
      sw3 = ron ? (zon ? i3 : 4) : -1;  s23 = (ron && zon) ? i3 : 4; }

    fvec4* outb = out + (size_t)b * 36 * HW4 + hw4;
#pragma unroll
    for (int k = 0; k < 9; ++k) {
        fvec4 ox, oy, oz, orr;
        const bool m0 = (k == sw0), m1 = (k == sw1), m2 = (k == sw2), m3 = (k == sw3);
        ox.x = m0 ? xv.x : 0.0f;  ox.y = m1 ? xv.y : 0.0f;
        ox.z = m2 ? xv.z : 0.0f;  ox.w = m3 ? xv.w : 0.0f;
        oy.x = m0 ? yv.x : 0.0f;  oy.y = m1 ? yv.y : 0.0f;
        oy.z = m2 ? yv.z : 0.0f;  oy.w = m3 ? yv.w : 0.0f;
        oz.x = m0 ? zv.x : 0.0f;  oz.y = m1 ? zv.y : 0.0f;
        oz.z = m2 ? zv.z : 0.0f;  oz.w = m3 ? zv.w : 0.0f;
        orr.x = (k == s20) ? rv.x : 0.0f;  orr.y = (k == s21) ? rv.y : 0.0f;
        orr.z = (k == s22) ? rv.z : 0.0f;  orr.w = (k == s23) ? rv.w : 0.0f;

        outb[(size_t)(4 * k + 0) * HW4] = ox;
        outb[(size_t)(4 * k + 1) * HW4] = oy;
        outb[(size_t)(4 * k + 2) * HW4] = oz;
        outb[(size_t)(4 * k + 3) * HW4] = orr;
    }
}

extern "C" void kernel_launch(void* const* d_in, const int* in_sizes, int n_in,
                              void* d_out, int out_size, void* d_ws, size_t ws_size,
                              hipStream_t stream) {
    const fvec4* x  = (const fvec4*)d_in[0];
    const fvec4* y  = (const fvec4*)d_in[1];
    const fvec4* z  = (const fvec4*)d_in[2];
    const fvec4* r  = (const fvec4*)d_in[3];
    const fvec4* kq = (const fvec4*)d_in[4];
    fvec4* out = (fvec4*)d_out;

    const size_t sel_bytes = (size_t)NB * HW;  // 1,228,800 B

    if (d_ws != nullptr && ws_size >= sel_bytes) {
        uchar4* sel = (uchar4*)d_ws;
        smap_sel_kernel<<<dim3(GRIDX, NB), dim3(BLK), 0, stream>>>(z, r, kq, sel);
        smap_scatter_kernel<<<dim3(36, CHUNKS, NB), dim3(BLK), 0, stream>>>(
            x, y, z, r, sel, out);
    } else {
        smap3x3_fused_kernel<<<dim3(GRIDX, NB), dim3(BLK), 0, stream>>>(
            x, y, z, r, kq, out);
    }
}